// Round 1
// baseline (813.341 us; speedup 1.0000x reference)
//
#include <hip/hip_runtime.h>
#include <math.h>

#define NTOK   4096
#define NFEAT  512
#define NDIM   64
#define RROWS  8
#define NBANDS (NTOK / RROWS)   // 512 bands per batch

// ---------------- block reductions (256 threads = 4 waves of 64) ----------------
__device__ __forceinline__ float block_max256(float v, float* s) {
#pragma unroll
  for (int o = 32; o > 0; o >>= 1) v = fmaxf(v, __shfl_down(v, o, 64));
  int tid = threadIdx.x;
  if ((tid & 63) == 0) s[tid >> 6] = v;
  __syncthreads();
  v = fmaxf(fmaxf(s[0], s[1]), fmaxf(s[2], s[3]));
  __syncthreads();
  return v;
}
__device__ __forceinline__ float block_sum256(float v, float* s) {
#pragma unroll
  for (int o = 32; o > 0; o >>= 1) v += __shfl_down(v, o, 64);
  int tid = threadIdx.x;
  if ((tid & 63) == 0) s[tid >> 6] = v;
  __syncthreads();
  v = s[0] + s[1] + s[2] + s[3];
  __syncthreads();
  return v;
}

// ---------------- QK projection + RoPE + initial charge ----------------
// grid 256 blocks (8192 rows / 32 rows per block), 256 threads.
__global__ __launch_bounds__(256) void qk_kernel(
    const float* __restrict__ feat, const float* __restrict__ cosb,
    const float* __restrict__ sinb, const float* __restrict__ Wq,
    const float* __restrict__ Wk, const float* __restrict__ cw,
    const float* __restrict__ cbp, float* __restrict__ Q, float* __restrict__ K,
    float* __restrict__ cur, float* __restrict__ chist)
{
  __shared__ __align__(16) float smem[32 * NFEAT];  // 64 KB, re-aliased later
  const int tid  = threadIdx.x;
  const int row0 = blockIdx.x * 32;  // global row index = b*4096 + n

  // stage 32x512 features, XOR bank swizzle: addr(r,c) = r*512 + (c ^ ((r&7)<<2))
  const float* fb = feat + (size_t)row0 * NFEAT;
  for (int i = tid; i < 32 * NFEAT; i += 256) {
    int r = i >> 9, c = i & 511;
    smem[(r << 9) + (c ^ ((r & 7) << 2))] = fb[i];
  }
  // zero charge history for these rows (4 steps per row)
  if (tid < 128) chist[row0 * 4 + tid] = 0.f;
  __syncthreads();

  const int r  = tid >> 3;  // 0..31  (row within block)
  const int cg = tid & 7;   // 0..7   (output column group: d = cg*8 + j)
  const int sw = (r & 7) << 2;
  const float* fr = smem + (r << 9);

  float accq[8] = {0, 0, 0, 0, 0, 0, 0, 0};
  float acck[8] = {0, 0, 0, 0, 0, 0, 0, 0};
  float accc = 0.f;
  for (int k = 0; k < NFEAT; ++k) {
    float fv = fr[k ^ sw];
    const float4 wq0 = *(const float4*)(Wq + k * NDIM + cg * 8);
    const float4 wq1 = *(const float4*)(Wq + k * NDIM + cg * 8 + 4);
    const float4 wk0 = *(const float4*)(Wk + k * NDIM + cg * 8);
    const float4 wk1 = *(const float4*)(Wk + k * NDIM + cg * 8 + 4);
    accq[0] = fmaf(fv, wq0.x, accq[0]); accq[1] = fmaf(fv, wq0.y, accq[1]);
    accq[2] = fmaf(fv, wq0.z, accq[2]); accq[3] = fmaf(fv, wq0.w, accq[3]);
    accq[4] = fmaf(fv, wq1.x, accq[4]); accq[5] = fmaf(fv, wq1.y, accq[5]);
    accq[6] = fmaf(fv, wq1.z, accq[6]); accq[7] = fmaf(fv, wq1.w, accq[7]);
    acck[0] = fmaf(fv, wk0.x, acck[0]); acck[1] = fmaf(fv, wk0.y, acck[1]);
    acck[2] = fmaf(fv, wk0.z, acck[2]); acck[3] = fmaf(fv, wk0.w, acck[3]);
    acck[4] = fmaf(fv, wk1.x, acck[4]); acck[5] = fmaf(fv, wk1.y, acck[5]);
    acck[6] = fmaf(fv, wk1.z, acck[6]); acck[7] = fmaf(fv, wk1.w, acck[7]);
    accc = fmaf(fv, cw[k], accc);  // all cg compute it; only cg==0 commits
  }
  __syncthreads();

  // re-alias smem as raw[32][132]: q in [0..63], k in [64..127]
  float* sraw = smem;
#pragma unroll
  for (int j = 0; j < 8; ++j) {
    sraw[r * 132 + cg * 8 + j]      = accq[j];
    sraw[r * 132 + 64 + cg * 8 + j] = acck[j];
  }
  if (cg == 0) {
    float cb = cbp[0];
    cur[row0 + r] = 1.f / (1.f + __expf(-(accc + cb)));
  }
  __syncthreads();

  // RoPE + store
  for (int i = tid; i < 32 * NDIM; i += 256) {
    int rr = i >> 6, d = i & 63;
    int g = row0 + rr, n = g & (NTOK - 1);
    float cv = cosb[(n << 6) + d], sv = sinb[(n << 6) + d];
    float qv = sraw[rr * 132 + d];
    float qr = (d < 32) ? -sraw[rr * 132 + d + 32] : sraw[rr * 132 + d - 32];
    Q[(size_t)g * NDIM + d] = qv * cv + qr * sv;
    float kv = sraw[rr * 132 + 64 + d];
    float kr = (d < 32) ? -sraw[rr * 132 + 64 + d + 32] : sraw[rr * 132 + 64 + d - 32];
    K[(size_t)g * NDIM + d] = kv * cv + kr * sv;
  }
}

// ---------------- compat = Q K^T / sqrt(64), lower-triangular 128x128 tiles ----------------
// grid 1056 blocks (2 batches * 528 lower tiles), 256 threads, 8x8 micro-tile.
__global__ __launch_bounds__(256) void compat_kernel(
    const float* __restrict__ Q, const float* __restrict__ K, float* __restrict__ C)
{
  __shared__ __align__(16) float Qs[32][132];
  __shared__ __align__(16) float Ks[32][132];
  int p = blockIdx.x, b = 0;
  if (p >= 528) { b = 1; p -= 528; }
  int ti = (int)((sqrtf(8.f * p + 1.f) - 1.f) * 0.5f);
  while ((ti + 1) * (ti + 2) / 2 <= p) ++ti;
  while (ti * (ti + 1) / 2 > p) --ti;
  int tj = p - ti * (ti + 1) / 2;

  const int tid = threadIdx.x;
  const int ty = tid >> 4, tx = tid & 15;
  const int i0 = ty * 8, j0 = tx * 8;
  const size_t qbase = ((size_t)b * NTOK + (size_t)ti * 128) * NDIM;
  const size_t kbase = ((size_t)b * NTOK + (size_t)tj * 128) * NDIM;

  float acc[8][8];
#pragma unroll
  for (int ii = 0; ii < 8; ++ii)
#pragma unroll
    for (int jj = 0; jj < 8; ++jj) acc[ii][jj] = 0.f;

  for (int dk = 0; dk < NDIM; dk += 32) {
    __syncthreads();
    // stage transposed: Qs[d][row], Ks[d][row]
    for (int i = tid; i < 128 * 32; i += 256) {
      int row = i >> 5, d = i & 31;
      Qs[d][row] = Q[qbase + (size_t)row * NDIM + dk + d];
      Ks[d][row] = K[kbase + (size_t)row * NDIM + dk + d];
    }
    __syncthreads();
#pragma unroll
    for (int d = 0; d < 32; ++d) {
      float4 a0 = *(const float4*)&Qs[d][i0];
      float4 a1 = *(const float4*)&Qs[d][i0 + 4];
      float4 b0 = *(const float4*)&Ks[d][j0];
      float4 b1 = *(const float4*)&Ks[d][j0 + 4];
      float av[8] = {a0.x, a0.y, a0.z, a0.w, a1.x, a1.y, a1.z, a1.w};
      float bv[8] = {b0.x, b0.y, b0.z, b0.w, b1.x, b1.y, b1.z, b1.w};
#pragma unroll
      for (int ii = 0; ii < 8; ++ii)
#pragma unroll
        for (int jj = 0; jj < 8; ++jj)
          acc[ii][jj] = fmaf(av[ii], bv[jj], acc[ii][jj]);
    }
  }
#pragma unroll
  for (int ii = 0; ii < 8; ++ii) {
    size_t grow = (size_t)b * NTOK + (size_t)ti * 128 + i0 + ii;
    float4 w0 = make_float4(acc[ii][0] * 0.125f, acc[ii][1] * 0.125f,
                            acc[ii][2] * 0.125f, acc[ii][3] * 0.125f);
    float4 w1 = make_float4(acc[ii][4] * 0.125f, acc[ii][5] * 0.125f,
                            acc[ii][6] * 0.125f, acc[ii][7] * 0.125f);
    *(float4*)&C[grow * NTOK + (size_t)tj * 128 + j0]     = w0;
    *(float4*)&C[grow * NTOK + (size_t)tj * 128 + j0 + 4] = w1;
  }
}

// ---------------- softmax sweep over the causal triangle ----------------
// logits_t[n,m] = compat[n,m] * (1 + ss * sum_tau chist[n][tau]*chist[m][tau])
// MODE 0: accumulate column sums of attn into per-band partials.
// MODE 1: write softmax rows to out (in-place over compat is safe: reads of a row
//         complete block-wide (reduction barriers) before that row is written).
// grid 1024 blocks (2 batches * 512 bands of 8 rows), 256 threads.
template <int MODE>
__global__ __launch_bounds__(256) void pass_kernel(
    const float* __restrict__ compat, const float4* __restrict__ chist,
    const float* __restrict__ ssp, float* __restrict__ partial,
    float* __restrict__ out)
{
  __shared__ float sred[4];
  const int tid = threadIdx.x;
  int band = blockIdx.x, b = 0;
  if (band >= NBANDS) { b = 1; band -= NBANDS; }
  const int n0 = band * RROWS;
  const float ss = ssp[0];

  float4 ch[16];
#pragma unroll
  for (int k = 0; k < 16; ++k) ch[k] = chist[(b << 12) + tid + (k << 8)];

  float cs[16];
#pragma unroll
  for (int k = 0; k < 16; ++k) cs[k] = 0.f;

  for (int rr = 0; rr < RROWS; ++rr) {
    const int n = n0 + rr;
    const float* rowp = compat + ((size_t)((b << 12) + n) << 12);
    float4 h = chist[(b << 12) + n];
    h.x *= ss; h.y *= ss; h.z *= ss; h.w *= ss;

    float e[16];
    float vmax = -INFINITY;
#pragma unroll
    for (int k = 0; k < 16; ++k) {
      const int col = tid + (k << 8);
      float x = -INFINITY;
      if (col <= n) {
        float cv  = rowp[col];
        float dot = fmaf(ch[k].x, h.x,
                    fmaf(ch[k].y, h.y, fmaf(ch[k].z, h.z, ch[k].w * h.w)));
        x = fmaf(cv, dot, cv);
      }
      e[k] = x;
      vmax = fmaxf(vmax, x);
    }
    float M = block_max256(vmax, sred);
    float lsum = 0.f;
#pragma unroll
    for (int k = 0; k < 16; ++k) {
      float v = __expf(e[k] - M);  // -inf -> 0
      e[k] = v;
      lsum += v;
    }
    float L = block_sum256(lsum, sred);
    float inv = 1.f / L;
    if (MODE == 0) {
#pragma unroll
      for (int k = 0; k < 16; ++k) cs[k] += e[k] * inv;
    } else {
      float* orow = out + ((size_t)((b << 12) + n) << 12);
#pragma unroll
      for (int k = 0; k < 16; ++k) orow[tid + (k << 8)] = e[k] * inv;
    }
  }
  if (MODE == 0) {
    float* pp = partial + ((size_t)b * NBANDS + band) * NTOK;
    const int cmax = n0 + RROWS - 1;
    const int kb = cmax >> 8;
    for (int k = 0; k <= kb; ++k) {
      int col = tid + (k << 8);
      if (col <= cmax) pp[col] = cs[k];
    }
  }
}

// ---------------- fold partials -> received, update charge ----------------
// grid 128 blocks (2 batches * 64), 256 threads (64 columns x 4 band segments).
__global__ __launch_bounds__(256) void reduce_update_kernel(
    const float* __restrict__ partial, const float* __restrict__ cdp,
    float* __restrict__ cur, float* __restrict__ chist, int step)
{
  __shared__ float s[4][64];
  const int tid = threadIdx.x;
  const int b = blockIdx.x >> 6;
  const int m0 = (blockIdx.x & 63) << 6;
  const int ml = tid & 63, seg = tid >> 6;
  const int m = m0 + ml;
  const int bmin = m >> 3;  // first band whose rows reach column m (RROWS=8)
  float sum = 0.f;
  const float* pb = partial + (size_t)b * NBANDS * NTOK + m;
  for (int band = bmin + seg; band < NBANDS; band += 4)
    sum += pb[(size_t)band << 12];
  s[seg][ml] = sum;
  __syncthreads();
  if (seg == 0) {
    float r = s[0][ml] + s[1][ml] + s[2][ml] + s[3][ml];
    float sg = 1.f / (1.f + __expf(-(r - 1.f)));
    float cd = cdp[0];
    int idx = (b << 12) + m;
    float c = cur[idx] * (1.f - cd * sg);
    cur[idx] = c;
    chist[idx * 4 + step] = c;
  }
}

extern "C" void kernel_launch(void* const* d_in, const int* in_sizes, int n_in,
                              void* d_out, int out_size, void* d_ws, size_t ws_size,
                              hipStream_t stream) {
  const float* feat = (const float*)d_in[0];
  const float* cosb = (const float*)d_in[1];
  const float* sinb = (const float*)d_in[2];
  // d_in[3] = mask: deterministic tril, handled structurally
  const float* Wq  = (const float*)d_in[4];
  const float* Wk  = (const float*)d_in[5];
  const float* cw  = (const float*)d_in[6];
  const float* cbp = (const float*)d_in[7];
  const float* ssp = (const float*)d_in[8];
  const float* cdp = (const float*)d_in[9];
  float* out = (float*)d_out;

  float* ws      = (float*)d_ws;
  float* Q       = ws;                 // 2*4096*64
  float* K       = ws + 524288;        // 2*4096*64
  float* chist   = ws + 1048576;       // 2*4096*4 (float4 per token)
  float* cur     = ws + 1081344;       // 2*4096
  float* partial = ws + 1089536;       // 2*512*4096

  // compat lives in d_out (134 MB); final pass overwrites it in place.
  qk_kernel<<<256, 256, 0, stream>>>(feat, cosb, sinb, Wq, Wk, cw, cbp, Q, K, cur, chist);
  compat_kernel<<<1056, 256, 0, stream>>>(Q, K, out);
  for (int t = 0; t < 4; ++t) {
    pass_kernel<0><<<2 * NBANDS, 256, 0, stream>>>(out, (const float4*)chist, ssp, partial, nullptr);
    reduce_update_kernel<<<128, 256, 0, stream>>>(partial, cdp, cur, chist, t);
  }
  pass_kernel<1><<<2 * NBANDS, 256, 0, stream>>>(out, (const float4*)chist, ssp, nullptr, out);
}

// Round 2
// 732.840 us; speedup vs baseline: 1.1098x; 1.1098x over previous
//
#include <hip/hip_runtime.h>
#include <math.h>

#define NTOK   4096
#define NFEAT  512
#define NDIM   64
#define RROWS  8
#define NBANDS (NTOK / RROWS)   // 512 bands per batch

// ---------------- block reductions (256 threads = 4 waves of 64) ----------------
__device__ __forceinline__ float block_max256(float v, float* s) {
#pragma unroll
  for (int o = 32; o > 0; o >>= 1) v = fmaxf(v, __shfl_down(v, o, 64));
  int tid = threadIdx.x;
  if ((tid & 63) == 0) s[tid >> 6] = v;
  __syncthreads();
  v = fmaxf(fmaxf(s[0], s[1]), fmaxf(s[2], s[3]));
  __syncthreads();
  return v;
}
__device__ __forceinline__ float block_sum256(float v, float* s) {
#pragma unroll
  for (int o = 32; o > 0; o >>= 1) v += __shfl_down(v, o, 64);
  int tid = threadIdx.x;
  if ((tid & 63) == 0) s[tid >> 6] = v;
  __syncthreads();
  v = s[0] + s[1] + s[2] + s[3];
  __syncthreads();
  return v;
}

// ---------------- QK projection + RoPE + initial charge ----------------
// grid 1024 blocks (8192 rows / 8 rows per block), 256 threads.
// thread = (r = tid>>5 in 0..7, c = tid&31); c<16 -> Q cols c*4.., c>=16 -> K cols.
__global__ __launch_bounds__(256) void qk_kernel(
    const float* __restrict__ feat, const float* __restrict__ cosb,
    const float* __restrict__ sinb, const float* __restrict__ Wq,
    const float* __restrict__ Wk, const float* __restrict__ cw,
    const float* __restrict__ cbp, float* __restrict__ Q, float* __restrict__ K,
    float* __restrict__ cur, float* __restrict__ chist)
{
  __shared__ __align__(16) float smem[RROWS * NFEAT];  // 16 KB
  const int tid  = threadIdx.x;
  const int row0 = blockIdx.x * RROWS;  // global row index = b*4096 + n

  // stage 8x512 features (float4 vectorized, no swizzle: 2-addr bank alias is free)
  const float4* fb4 = (const float4*)(feat + (size_t)row0 * NFEAT);
  float4* sm4 = (float4*)smem;
#pragma unroll
  for (int i = tid; i < RROWS * NFEAT / 4; i += 256) sm4[i] = fb4[i];
  if (tid < RROWS * 4) chist[row0 * 4 + tid] = 0.f;
  __syncthreads();

  const int r   = tid >> 5;        // 0..7
  const int c   = tid & 31;        // 0..31
  const int isQ = (c < 16);
  const int d0  = (c & 15) * 4;
  const float* __restrict__ Wp = isQ ? Wq : Wk;
  const float* fr = smem + (r << 9);

  float a0 = 0.f, a1 = 0.f, a2 = 0.f, a3 = 0.f;
  for (int k = 0; k < NFEAT; ++k) {
    float fv = fr[k];
    float4 w = *(const float4*)(Wp + k * NDIM + d0);
    a0 = fmaf(fv, w.x, a0); a1 = fmaf(fv, w.y, a1);
    a2 = fmaf(fv, w.z, a2); a3 = fmaf(fv, w.w, a3);
  }

  // charge: row dot cw, strided over 32 lanes then shuffle-reduce within the row's lane group
  float accc = 0.f;
#pragma unroll
  for (int j = 0; j < 16; ++j) accc = fmaf(fr[c + (j << 5)], cw[c + (j << 5)], accc);
#pragma unroll
  for (int o = 16; o > 0; o >>= 1) accc += __shfl_down(accc, o, 64);
  if (c == 0) {
    float cb = cbp[0];
    cur[row0 + r] = 1.f / (1.f + __expf(-(accc + cb)));
  }
  __syncthreads();

  // re-alias smem as raw[8][132]: q in [0..63], k in [64..127]
  float* sraw = smem;
  {
    float* dst = sraw + r * 132 + (isQ ? 0 : 64) + d0;
    dst[0] = a0; dst[1] = a1; dst[2] = a2; dst[3] = a3;
  }
  __syncthreads();

  // RoPE + store (8 rows x 64 dims = 512 work items)
#pragma unroll
  for (int i = tid; i < RROWS * NDIM; i += 256) {
    int rr = i >> 6, d = i & 63;
    int g = row0 + rr, n = g & (NTOK - 1);
    float cv = cosb[(n << 6) + d], sv = sinb[(n << 6) + d];
    float qv = sraw[rr * 132 + d];
    float qr = (d < 32) ? -sraw[rr * 132 + d + 32] : sraw[rr * 132 + d - 32];
    Q[(size_t)g * NDIM + d] = qv * cv + qr * sv;
    float kv = sraw[rr * 132 + 64 + d];
    float kr = (d < 32) ? -sraw[rr * 132 + 64 + d + 32] : sraw[rr * 132 + 64 + d - 32];
    K[(size_t)g * NDIM + d] = kv * cv + kr * sv;
  }
}

// ---------------- compat = Q K^T / sqrt(64), lower-triangular 128x128 tiles ----------------
// grid 1056 blocks (2 batches * 528 lower tiles), 256 threads, 8x8 micro-tile.
__global__ __launch_bounds__(256) void compat_kernel(
    const float* __restrict__ Q, const float* __restrict__ K, float* __restrict__ C)
{
  __shared__ __align__(16) float Qs[32][132];
  __shared__ __align__(16) float Ks[32][132];
  int p = blockIdx.x, b = 0;
  if (p >= 528) { b = 1; p -= 528; }
  int ti = (int)((sqrtf(8.f * p + 1.f) - 1.f) * 0.5f);
  while ((ti + 1) * (ti + 2) / 2 <= p) ++ti;
  while (ti * (ti + 1) / 2 > p) --ti;
  int tj = p - ti * (ti + 1) / 2;

  const int tid = threadIdx.x;
  const int ty = tid >> 4, tx = tid & 15;
  const int i0 = ty * 8, j0 = tx * 8;
  const size_t qbase = ((size_t)b * NTOK + (size_t)ti * 128) * NDIM;
  const size_t kbase = ((size_t)b * NTOK + (size_t)tj * 128) * NDIM;

  float acc[8][8];
#pragma unroll
  for (int ii = 0; ii < 8; ++ii)
#pragma unroll
    for (int jj = 0; jj < 8; ++jj) acc[ii][jj] = 0.f;

  for (int dk = 0; dk < NDIM; dk += 32) {
    __syncthreads();
    for (int i = tid; i < 128 * 32; i += 256) {
      int row = i >> 5, d = i & 31;
      Qs[d][row] = Q[qbase + (size_t)row * NDIM + dk + d];
      Ks[d][row] = K[kbase + (size_t)row * NDIM + dk + d];
    }
    __syncthreads();
#pragma unroll
    for (int d = 0; d < 32; ++d) {
      float4 q0 = *(const float4*)&Qs[d][i0];
      float4 q1 = *(const float4*)&Qs[d][i0 + 4];
      float4 k0 = *(const float4*)&Ks[d][j0];
      float4 k1 = *(const float4*)&Ks[d][j0 + 4];
      float av[8] = {q0.x, q0.y, q0.z, q0.w, q1.x, q1.y, q1.z, q1.w};
      float bv[8] = {k0.x, k0.y, k0.z, k0.w, k1.x, k1.y, k1.z, k1.w};
#pragma unroll
      for (int ii = 0; ii < 8; ++ii)
#pragma unroll
        for (int jj = 0; jj < 8; ++jj)
          acc[ii][jj] = fmaf(av[ii], bv[jj], acc[ii][jj]);
    }
  }
#pragma unroll
  for (int ii = 0; ii < 8; ++ii) {
    size_t grow = (size_t)b * NTOK + (size_t)ti * 128 + i0 + ii;
    float4 w0 = make_float4(acc[ii][0] * 0.125f, acc[ii][1] * 0.125f,
                            acc[ii][2] * 0.125f, acc[ii][3] * 0.125f);
    float4 w1 = make_float4(acc[ii][4] * 0.125f, acc[ii][5] * 0.125f,
                            acc[ii][6] * 0.125f, acc[ii][7] * 0.125f);
    *(float4*)&C[grow * NTOK + (size_t)tj * 128 + j0]     = w0;
    *(float4*)&C[grow * NTOK + (size_t)tj * 128 + j0 + 4] = w1;
  }
}

// ---------------- softmax sweep over the causal triangle ----------------
// logits_t[n,m] = compat[n,m] * (1 + ss * sum_tau chist[n][tau]*chist[m][tau])
// Chunk-skip: only chunks k <= kmax=(n0+7)>>8 touched, via UNIFORM branches inside
// static-unrolled loops (keeps e[]/ch[] in registers — no dynamic indexing).
template <int MODE>
__global__ __launch_bounds__(256) void pass_kernel(
    const float* __restrict__ compat, const float4* __restrict__ chist,
    const float* __restrict__ ssp, float* __restrict__ partial,
    float* __restrict__ out)
{
  __shared__ float sred[4];
  const int tid = threadIdx.x;
  int band = blockIdx.x, b = 0;
  if (band >= NBANDS) { b = 1; band -= NBANDS; }
  const int n0 = band * RROWS;
  const int kmax = (n0 + RROWS - 1) >> 8;  // last chunk with any col <= n
  const float ss = ssp[0];

  float4 ch[16];
#pragma unroll
  for (int k = 0; k < 16; ++k)
    if (k <= kmax) ch[k] = chist[(b << 12) + tid + (k << 8)];

  float cs[16];
#pragma unroll
  for (int k = 0; k < 16; ++k) cs[k] = 0.f;

  for (int rr = 0; rr < RROWS; ++rr) {
    const int n = n0 + rr;
    const float* rowp = compat + ((size_t)((b << 12) + n) << 12);
    float4 h = chist[(b << 12) + n];
    h.x *= ss; h.y *= ss; h.z *= ss; h.w *= ss;

    float e[16];
    float vmax = -INFINITY;
#pragma unroll
    for (int k = 0; k < 16; ++k) {
      if (k > kmax) continue;                 // uniform skip
      const int col = tid + (k << 8);
      float x = -INFINITY;
      if (col <= n) {
        float cv  = rowp[col];
        float dot = fmaf(ch[k].x, h.x,
                    fmaf(ch[k].y, h.y, fmaf(ch[k].z, h.z, ch[k].w * h.w)));
        x = fmaf(cv, dot, cv);
      }
      e[k] = x;
      vmax = fmaxf(vmax, x);
    }
    float M = block_max256(vmax, sred);
    float lsum = 0.f;
#pragma unroll
    for (int k = 0; k < 16; ++k) {
      if (k > kmax) continue;
      float v = __expf(e[k] - M);  // -inf -> 0
      e[k] = v;
      lsum += v;
    }
    float L = block_sum256(lsum, sred);
    float inv = 1.f / L;
    if (MODE == 0) {
#pragma unroll
      for (int k = 0; k < 16; ++k)
        if (k <= kmax) cs[k] += e[k] * inv;
    } else {
      float* orow = out + ((size_t)((b << 12) + n) << 12);
#pragma unroll
      for (int k = 0; k < 16; ++k) {
        if (k <= kmax) orow[tid + (k << 8)] = e[k] * inv;
        else           orow[tid + (k << 8)] = 0.f;
      }
    }
  }
  if (MODE == 0) {
    float* pp = partial + ((size_t)b * NBANDS + band) * NTOK;
    const int cmax = n0 + RROWS - 1;
#pragma unroll
    for (int k = 0; k < 16; ++k) {
      if (k > kmax) continue;
      int col = tid + (k << 8);
      if (col <= cmax) pp[col] = cs[k];
    }
  }
}

// ---------------- fold partials -> received, update charge ----------------
// grid 256 blocks (2 batches * 128 col-groups of 32), 256 threads (32 cols x 8 segs).
__global__ __launch_bounds__(256) void reduce_update_kernel(
    const float* __restrict__ partial, const float* __restrict__ cdp,
    float* __restrict__ cur, float* __restrict__ chist, int step)
{
  __shared__ float s[8][32];
  const int tid = threadIdx.x;
  const int b = blockIdx.x >> 7;
  const int m0 = (blockIdx.x & 127) << 5;
  const int ml = tid & 31, seg = tid >> 5;
  const int m = m0 + ml;
  const int bmin = m >> 3;  // first band whose rows reach column m (RROWS=8)
  float sum = 0.f;
  const float* pb = partial + (size_t)b * NBANDS * NTOK + m;
  for (int band = bmin + seg; band < NBANDS; band += 8)
    sum += pb[(size_t)band << 12];
  s[seg][ml] = sum;
  __syncthreads();
  if (seg == 0) {
    float r = s[0][ml] + s[1][ml] + s[2][ml] + s[3][ml] +
              s[4][ml] + s[5][ml] + s[6][ml] + s[7][ml];
    float sg = 1.f / (1.f + __expf(-(r - 1.f)));
    float cd = cdp[0];
    int idx = (b << 12) + m;
    float c = cur[idx] * (1.f - cd * sg);
    cur[idx] = c;
    chist[idx * 4 + step] = c;
  }
}

extern "C" void kernel_launch(void* const* d_in, const int* in_sizes, int n_in,
                              void* d_out, int out_size, void* d_ws, size_t ws_size,
                              hipStream_t stream) {
  const float* feat = (const float*)d_in[0];
  const float* cosb = (const float*)d_in[1];
  const float* sinb = (const float*)d_in[2];
  // d_in[3] = mask: deterministic tril, handled structurally
  const float* Wq  = (const float*)d_in[4];
  const float* Wk  = (const float*)d_in[5];
  const float* cw  = (const float*)d_in[6];
  const float* cbp = (const float*)d_in[7];
  const float* ssp = (const float*)d_in[8];
  const float* cdp = (const float*)d_in[9];
  float* out = (float*)d_out;

  float* ws      = (float*)d_ws;
  float* Q       = ws;                 // 2*4096*64
  float* K       = ws + 524288;        // 2*4096*64
  float* chist   = ws + 1048576;       // 2*4096*4 (float4 per token)
  float* cur     = ws + 1081344;       // 2*4096
  float* partial = ws + 1089536;       // 2*512*4096

  // compat lives in d_out (134 MB); final pass overwrites it in place.
  qk_kernel<<<1024, 256, 0, stream>>>(feat, cosb, sinb, Wq, Wk, cw, cbp, Q, K, cur, chist);
  compat_kernel<<<1056, 256, 0, stream>>>(Q, K, out);
  for (int t = 0; t < 4; ++t) {
    pass_kernel<0><<<2 * NBANDS, 256, 0, stream>>>(out, (const float4*)chist, ssp, partial, nullptr);
    reduce_update_kernel<<<256, 256, 0, stream>>>(partial, cdp, cur, chist, t);
  }
  pass_kernel<1><<<2 * NBANDS, 256, 0, stream>>>(out, (const float4*)chist, ssp, nullptr, out);
}